// Round 8
// baseline (1007.716 us; speedup 1.0000x reference)
//
#include <hip/hip_runtime.h>
#include <cstdint>
#include <cstddef>

#define T_DIM 4
#define B_DIM 32
#define C_DIM 256
#define N_DIM 1024
#define NHEAD 8
#define DHEAD 32
#define NWRD 32   // N/32 bit-words per row

// LIF step, exact reference rounding: v += (x-v)/2; s = v>=vth; hard reset.
__device__ __forceinline__ float lif_step(float& v, float x, float vth) {
    v = __fadd_rn(v, __fmul_rn(__fsub_rn(x, v), 0.5f));
    const float s = (v >= vth) ? 1.0f : 0.0f;
    if (s != 0.0f) v = 0.0f;
    return s;
}

// async global->LDS, 16B per lane. LDS dest = wave-uniform base + lane*16.
__device__ __forceinline__ void async_copy16(const float* g, float* l) {
    __builtin_amdgcn_global_load_lds(
        (const __attribute__((address_space(1))) unsigned int*)g,
        (__attribute__((address_space(3))) unsigned int*)l, 16, 0, 0);
}

// one a-element times 4 cols, strict k-ascending chains per acc element
#define FMA_ROW4(r, av)                               \
    acc[(r)*4+0] = fmaf(av, b0.x, acc[(r)*4+0]);      \
    acc[(r)*4+1] = fmaf(av, b0.y, acc[(r)*4+1]);      \
    acc[(r)*4+2] = fmaf(av, b0.z, acc[(r)*4+2]);      \
    acc[(r)*4+3] = fmaf(av, b0.w, acc[(r)*4+3]);

#define FMA_8x4()        \
    FMA_ROW4(0, a0.x)    \
    FMA_ROW4(1, a0.y)    \
    FMA_ROW4(2, a0.z)    \
    FMA_ROW4(3, a0.w)    \
    FMA_ROW4(4, a1.x)    \
    FMA_ROW4(5, a1.y)    \
    FMA_ROW4(6, a1.z)    \
    FMA_ROW4(7, a1.w)

// Pre-transpose: wqk_t[k][h*64+j] = (j<32 ? qw[h*32+j][k] : kw[h*32+j-32][k])
//                p_t[k][c] = pw[c][k]
__global__ __launch_bounds__(256) void k_transpose(
    const float* __restrict__ qw, const float* __restrict__ kw,
    const float* __restrict__ pw, float* __restrict__ wqk_t,
    float* __restrict__ p_t)
{
    const int i = blockIdx.x * 256 + threadIdx.x;
    if (i < C_DIM * 512) {
        const int k = i >> 9, col = i & 511;
        const int h = col >> 6, j = col & 63;
        wqk_t[i] = (j < 32) ? qw[(size_t)(h * 32 + j) * C_DIM + k]
                            : kw[(size_t)(h * 32 + j - 32) * C_DIM + k];
    } else {
        const int i2 = i - C_DIM * 512;            // < 65536
        const int k = i2 >> 8, c = i2 & 255;
        p_t[i2] = pw[(size_t)c * C_DIM + k];
    }
}

// K1: 2 heads per block. grid (N/128, B, NHEAD/2) -> hp-siblings (same nt,b)
// have linear-id stride 256 === 0 mod 8 -> same XCD -> x L2-shared.
// Block tile m=128, n=128, BK=32; thread tile 8x4. Only x staged in LDS
// (double-buffered, global_load_lds); w-fragments (a0/a1) read directly from
// global: wqk_t is 512KB L2-resident and 32 lanes/wave share each address
// (L1 broadcast) -> LDS pipe carries 1 b128/k instead of 3 (it was
// co-limiting with VALU at round 5/7's ~70% VALUBusy). w loads have no
// barrier coupling -> compiler pipelines them across k.
// ONE barrier per chunk; 32 chunks = 4 t x 8 k-chunks.
__global__ __launch_bounds__(512, 4) void k_qk(
    const float* __restrict__ x, const float* __restrict__ wqk,   // [256][512]
    const float* __restrict__ qg, const float* __restrict__ qbeta,
    const float* __restrict__ qmean, const float* __restrict__ qvar,
    const float* __restrict__ kg, const float* __restrict__ kbeta,
    const float* __restrict__ kmean, const float* __restrict__ kvar,
    uint32_t* __restrict__ xbits)
{
    __shared__ float x_lds[2][32 * 128];   // [buf][k][n] 2x16 KB
    __shared__ float inv_lds[128];
    __shared__ float bias_lds[128];
    __shared__ float    qsum_lds[256];     // dedicated epilogue scratch
    __shared__ float    attn_lds[256];
    __shared__ uint32_t pack_lds[256];

    const int tid = threadIdx.x;
    const int nt = blockIdx.x, b = blockIdx.y, hp = blockIdx.z;
    const int n0g = nt * 128;

    const int  mg   = tid >> 5;        // 0..15 -> rows mg*8..+7
    const int  m0   = mg << 3;
    const int  ng   = tid & 31;
    const int  n0   = ng << 2;         // cols n0..n0+3
    const int  hsel = mg >> 3;
    const bool is_q = ((mg & 7) < 4);  // wave-uniform (2 mg per wave)

    if (tid < 128) {
        const int m = tid;
        const int hs = m >> 6, j = m & 63;
        const int h = hp * 2 + hs;
        const bool q = (j < 32);
        const float* g  = q ? qg    : kg;
        const float* be = q ? qbeta : kbeta;
        const float* me = q ? qmean : kmean;
        const float* va = q ? qvar  : kvar;
        const int ch = h * DHEAD + (q ? j : j - 32);
        const float iv = __fdiv_rn(g[ch], __fsqrt_rn(__fadd_rn(va[ch], 1e-5f)));
        inv_lds[m]  = iv;
        bias_lds[m] = __fsub_rn(be[ch], __fmul_rn(me[ch], iv));
    }

    // x staging: round r covers k-row r*16 + skl, cols scol..+3
    const int skl  = tid >> 5;         // 0..15
    const int scol = (tid & 31) << 2;

    float vstate[32];
    #pragma unroll
    for (int i = 0; i < 32; i++) vstate[i] = 0.0f;
    float v_attn = 0.0f;

    // stage chunk 0 into buf 0
    {
        const float* xgp = x + ((size_t)b * C_DIM + skl) * N_DIM + n0g + scol;
        #pragma unroll
        for (int r = 0; r < 2; r++)
            async_copy16(xgp + (size_t)(r * 16) * N_DIM, &x_lds[0][r * 2048 + tid * 4]);
    }

    float acc[32];
    #pragma unroll
    for (int i = 0; i < 32; i++) acc[i] = 0.0f;

    for (int g = 0; g < 32; ++g) {
        const int cur = g & 1;
        __syncthreads();   // drains stage(g) (in flight a full compute phase);
                           // joins readers of buf[1-cur] (chunk g-1)
        if (g + 1 < 32) {  // stage chunk g+1 into the other buffer
            const int g1 = g + 1, tt = g1 >> 3, kk = (g1 & 7) * 32;
            const float* xgp = x + ((size_t)(tt * B_DIM + b) * C_DIM + kk + skl) * N_DIM
                               + n0g + scol;
            float* xd = &x_lds[1 - cur][0];
            #pragma unroll
            for (int r = 0; r < 2; r++)
                async_copy16(xgp + (size_t)(r * 16) * N_DIM, xd + r * 2048 + tid * 4);
        }
        {
            const float* wg = wqk + (size_t)((g & 7) * 32) * 512 + hp * 128 + m0;
            const float* xl = &x_lds[cur][0];
            #pragma unroll 2
            for (int k = 0; k < 32; k++) {
                const float4 a0 = *(const float4*)(wg + (size_t)k * 512);
                const float4 a1 = *(const float4*)(wg + (size_t)k * 512 + 4);
                const float4 b0 = *(const float4*)(xl + k * 128 + n0);
                FMA_8x4()
            }
        }

        if ((g & 7) == 7) {   // end of one t: BN + LIF + attn + pack epilogue
            const int t = g >> 3;
            #pragma unroll
            for (int r = 0; r < 8; r++) {
                const float iv = inv_lds[m0 + r];
                const float bs = bias_lds[m0 + r];
                #pragma unroll
                for (int j = 0; j < 4; j++) {
                    const float y = __fadd_rn(__fmul_rn(acc[r * 4 + j], iv), bs);
                    acc[r * 4 + j] = lif_step(vstate[r * 4 + j], y, 1.0f);
                }
            }
            if (tid < 256) { qsum_lds[tid] = 0.0f; pack_lds[tid] = 0u; }
            __syncthreads();
            if (is_q) {
                #pragma unroll
                for (int j = 0; j < 4; j++) {
                    const int col = n0 + j;
                    float cs = acc[j];
                    #pragma unroll
                    for (int r = 1; r < 8; r++) cs += acc[r * 4 + j];
                    atomicAdd(&qsum_lds[hsel * 128 + col], cs);
                }
            }
            __syncthreads();
            if (tid < 256) attn_lds[tid] = lif_step(v_attn, qsum_lds[tid], 0.5f);
            __syncthreads();
            if (!is_q) {
                #pragma unroll
                for (int r = 0; r < 8; r++) {
                    const int krow = ((mg & 7) - 4) * 8 + r;
                    uint32_t nib = 0;
                    #pragma unroll
                    for (int jj = 0; jj < 4; jj++) {
                        if (acc[r * 4 + jj] != 0.0f &&
                            attn_lds[hsel * 128 + n0 + jj] != 0.0f)
                            nib |= (1u << jj);
                    }
                    if (nib) {
                        const int word = ng >> 3;
                        const int shf  = (ng & 7) * 4;
                        atomicOr(&pack_lds[hsel * 128 + krow * 4 + word], nib << shf);
                    }
                }
            }
            __syncthreads();
            if (tid < 256) {
                const int hs2  = tid >> 7;
                const int rem  = tid & 127;
                const int krow = rem >> 2, word = rem & 3;
                const int ch = (hp * 2 + hs2) * DHEAD + krow;
                xbits[((size_t)(t * B_DIM + b) * C_DIM + ch) * NWRD + nt * 4 + word]
                    = pack_lds[tid];
            }
            // reset acc for next t (registers)
            #pragma unroll
            for (int i = 0; i < 32; i++) acc[i] = 0.0f;
            // next loop-top barrier protects scratch before next epilogue
        }
    }
}

// K2: projection GEMM. grid (N/128, B, C/128) -> mt-siblings stride 256 ===
// 0 mod 8 -> same XCD (xbits L2-shared). Block tile m=128, n=128, BK=32;
// thread tile 8x4. Only x in LDS (bit-unpacked, double-buffered); w-fragments
// read directly from global (p_t 256KB, L2-resident, wave-broadcast).
// Bits pipelined 2 chunks ahead. ONE barrier per chunk; epilogue LDS-free.
__global__ __launch_bounds__(512, 4) void k_proj(
    const uint32_t* __restrict__ xbits, const float* __restrict__ pt,  // [256][256]
    const float* __restrict__ pbias, const float* __restrict__ pg,
    const float* __restrict__ pbeta, const float* __restrict__ pmean,
    const float* __restrict__ pvar, float* __restrict__ out)
{
    __shared__ float x_lds[2][32 * 128];
    __shared__ float inv_lds[128];
    __shared__ float bias_lds[128];
    __shared__ float pb_lds[128];

    const int tid = threadIdx.x;
    const int nt = blockIdx.x, b = blockIdx.y, mt = blockIdx.z;
    const int n0g = nt * 128;
    const int c0  = mt * 128;

    const int mg = tid >> 5, m0 = mg << 3;
    const int ng = tid & 31, n0 = ng << 2;

    if (tid < 128) {
        const int ch = c0 + tid;
        const float iv = __fdiv_rn(pg[ch], __fsqrt_rn(__fadd_rn(pvar[ch], 1e-5f)));
        inv_lds[tid]  = iv;
        bias_lds[tid] = __fsub_rn(pbeta[ch], __fmul_rn(pmean[ch], iv));
        pb_lds[tid]   = pbias[ch];
    }

    // unpack: thread -> chunk k-row urow (0..31), 8 cols at cg*8
    const int urow = tid >> 4, cg = tid & 15;
    const int wsel = nt * 4 + (cg >> 2);
    const int ushf = (cg & 3) * 8;

    float vstate[32];
    #pragma unroll
    for (int i = 0; i < 32; i++) vstate[i] = 0.0f;

    // bits word for global chunk G: xbits[((G>>3)*B+b)*C*NWRD + ((G&7)*32+urow)*NWRD + wsel]
    #define BITS_AT(G) xbits[((size_t)((G) >> 3) * B_DIM + b) * C_DIM * NWRD \
                             + (size_t)(((G) & 7) * 32 + urow) * NWRD + wsel]

    // prologue: unpack chunk 0 into buf0; preload bits(1)
    {
        const uint32_t u0 = BITS_AT(0);
        const uint32_t bits = (u0 >> ushf) & 0xffu;
        float* xw = &x_lds[0][urow * 128 + cg * 8];
        float4 f0, f1;
        f0.x = ((bits >> 0) & 1u) ? 1.0f : 0.0f;
        f0.y = ((bits >> 1) & 1u) ? 1.0f : 0.0f;
        f0.z = ((bits >> 2) & 1u) ? 1.0f : 0.0f;
        f0.w = ((bits >> 3) & 1u) ? 1.0f : 0.0f;
        f1.x = ((bits >> 4) & 1u) ? 1.0f : 0.0f;
        f1.y = ((bits >> 5) & 1u) ? 1.0f : 0.0f;
        f1.z = ((bits >> 6) & 1u) ? 1.0f : 0.0f;
        f1.w = ((bits >> 7) & 1u) ? 1.0f : 0.0f;
        *(float4*)(xw)     = f0;
        *(float4*)(xw + 4) = f1;
    }
    uint32_t u_a = BITS_AT(1);

    float acc[32];
    #pragma unroll
    for (int i = 0; i < 32; i++) acc[i] = 0.0f;

    for (int g = 0; g < 32; ++g) {
        const int cur = g & 1;
        __syncthreads();   // joins unpack writes for chunk g with readers
        if (g + 1 < 32) {  // prepare chunk g+1 in the other buffer
            const uint32_t bits = (u_a >> ushf) & 0xffu;
            float* xw = &x_lds[1 - cur][urow * 128 + cg * 8];
            float4 f0, f1;
            f0.x = ((bits >> 0) & 1u) ? 1.0f : 0.0f;
            f0.y = ((bits >> 1) & 1u) ? 1.0f : 0.0f;
            f0.z = ((bits >> 2) & 1u) ? 1.0f : 0.0f;
            f0.w = ((bits >> 3) & 1u) ? 1.0f : 0.0f;
            f1.x = ((bits >> 4) & 1u) ? 1.0f : 0.0f;
            f1.y = ((bits >> 5) & 1u) ? 1.0f : 0.0f;
            f1.z = ((bits >> 6) & 1u) ? 1.0f : 0.0f;
            f1.w = ((bits >> 7) & 1u) ? 1.0f : 0.0f;
            *(float4*)(xw)     = f0;
            *(float4*)(xw + 4) = f1;
        }
        if (g + 2 < 32) u_a = BITS_AT(g + 2);   // hidden under compute(g)
        {
            const float* wg = pt + (size_t)((g & 7) * 32) * 256 + c0 + m0;
            const float* xl = &x_lds[cur][0];
            #pragma unroll 2
            for (int k = 0; k < 32; k++) {
                const float4 a0 = *(const float4*)(wg + (size_t)k * 256);
                const float4 a1 = *(const float4*)(wg + (size_t)k * 256 + 4);
                const float4 b0 = *(const float4*)(xl + k * 128 + n0);
                FMA_8x4()
            }
        }

        if ((g & 7) == 7) {   // end of t: bias + BN + LIF + store (regs + global)
            const int t = g >> 3;
            #pragma unroll
            for (int r = 0; r < 8; r++) {
                const int ch = c0 + m0 + r;
                const float iv = inv_lds[m0 + r];
                const float bs = bias_lds[m0 + r];
                const float pb = pb_lds[m0 + r];
                float* ob = out + ((size_t)(t * B_DIM + b) * C_DIM + ch) * N_DIM + n0g;
                float ov[4];
                #pragma unroll
                for (int j = 0; j < 4; j++) {
                    float y = __fadd_rn(acc[r * 4 + j], pb);
                    y = __fadd_rn(__fmul_rn(y, iv), bs);
                    ov[j] = lif_step(vstate[r * 4 + j], y, 1.0f);
                }
                float4 o4;
                o4.x = ov[0]; o4.y = ov[1]; o4.z = ov[2]; o4.w = ov[3];
                *(float4*)(ob + n0) = o4;
            }
            #pragma unroll
            for (int i = 0; i < 32; i++) acc[i] = 0.0f;
        }
    }
    #undef BITS_AT
}

extern "C" void kernel_launch(void* const* d_in, const int* in_sizes, int n_in,
                              void* d_out, int out_size, void* d_ws, size_t ws_size,
                              hipStream_t stream) {
    const float* x    = (const float*)d_in[0];
    const float* q_w  = (const float*)d_in[1];
    const float* q_g  = (const float*)d_in[2];
    const float* q_b  = (const float*)d_in[3];
    const float* q_m  = (const float*)d_in[4];
    const float* q_v  = (const float*)d_in[5];
    const float* k_w  = (const float*)d_in[6];
    const float* k_g  = (const float*)d_in[7];
    const float* k_b  = (const float*)d_in[8];
    const float* k_m  = (const float*)d_in[9];
    const float* k_v  = (const float*)d_in[10];
    const float* p_w  = (const float*)d_in[11];
    const float* p_b  = (const float*)d_in[12];
    const float* p_g  = (const float*)d_in[13];
    const float* p_be = (const float*)d_in[14];
    const float* p_m  = (const float*)d_in[15];
    const float* p_v  = (const float*)d_in[16];

    // ws layout: wqk_t 512KB | p_t 256KB | xbits 4MB
    float*    wqk_t = (float*)d_ws;
    float*    p_t   = (float*)((char*)d_ws + 524288);
    uint32_t* xbits = (uint32_t*)((char*)d_ws + 786432);
    float*    out   = (float*)d_out;

    k_transpose<<<768, 256, 0, stream>>>(q_w, k_w, p_w, wqk_t, p_t);

    dim3 g1(N_DIM / 128, B_DIM, NHEAD / 2);
    k_qk<<<g1, 512, 0, stream>>>(x, wqk_t, q_g, q_b, q_m, q_v,
                                 k_g, k_b, k_m, k_v, xbits);

    dim3 g2(N_DIM / 128, B_DIM, C_DIM / 128);
    k_proj<<<g2, 512, 0, stream>>>(xbits, p_t, p_b, p_g, p_be, p_m, p_v, out);
}